// Round 15
// baseline (552.000 us; speedup 1.0000x reference)
//
#include <hip/hip_runtime.h>

#define NN 50000
#define EE 800000
#define FIN 16
#define EDIM 4
#define EMB 32
#define NH 4
#define HC 128          // EMB*NH
#define NL 2
#define DENSE 128
#define QNPB 50         // nodes per qkvs/ftq/head block (50000 = 1000 * 50)
#define SBLK 49         // scan blocks: ceil(50000/1024)
#define SCATB ((EE + 255) / 256)   // 3125 scatter blocks in the fused kernel

typedef _Float16 h2 __attribute__((ext_vector_type(2)));
union HU { unsigned int u; h2 h; };

__device__ __forceinline__ h2 u2h(unsigned int u) { HU c; c.u = u; return c.h; }
__device__ __forceinline__ unsigned int h2u(h2 h) { HU c; c.h = h; return c.u; }

// fdot2: f32 += h2 . h2 — hedge builtin availability with a scalar fallback
#if defined(__has_builtin)
#  if __has_builtin(__builtin_amdgcn_fdot2)
#    define FDOT2(a, b, c) __builtin_amdgcn_fdot2((a), (b), (c), false)
#  endif
#endif
#ifndef FDOT2
__device__ __forceinline__ float fdot2_sw(h2 a, h2 b, float c) {
    return fmaf((float)a.x, (float)b.x, fmaf((float)a.y, (float)b.y, c));
}
#  define FDOT2(a, b, c) fdot2_sw((a), (b), (c))
#endif

// unpack two packed fp16 -> float2
__device__ __forceinline__ float2 h2f2(unsigned int u) {
    union { unsigned int u; _Float16 h[2]; } c; c.u = u;
    return make_float2((float)c.h[0], (float)c.h[1]);
}
__device__ __forceinline__ unsigned int pkh2(float a, float b) {
    union { unsigned int u; _Float16 h[2]; } c;
    c.h[0] = (_Float16)a; c.h[1] = (_Float16)b; return c.u;
}

// ---------------- CSR build ----------------
__global__ void hist_kernel(const int* __restrict__ dst, int* __restrict__ counts) {
    int e = blockIdx.x * blockDim.x + threadIdx.x;
    if (e < EE) atomicAdd(&counts[dst[e]], 1);
}

__global__ __launch_bounds__(1024) void scan1_kernel(const int* __restrict__ cursor,
                                                     int* __restrict__ row_ptr,
                                                     int* __restrict__ bsum) {
    __shared__ int wsum[16];
    __shared__ int wpre[17];
    int tid = threadIdx.x, lane = tid & 63, wid = tid >> 6;
    int i = blockIdx.x * 1024 + tid;
    int v = (i < NN) ? cursor[i] : 0;
    int incl = v;
    #pragma unroll
    for (int off = 1; off < 64; off <<= 1) {
        int t = __shfl_up(incl, off, 64);
        if (lane >= off) incl += t;
    }
    if (lane == 63) wsum[wid] = incl;
    __syncthreads();
    if (tid == 0) {
        int acc = 0;
        #pragma unroll
        for (int w = 0; w < 16; ++w) { wpre[w] = acc; acc += wsum[w]; }
        wpre[16] = acc;
    }
    __syncthreads();
    if (i < NN) row_ptr[i] = wpre[wid] + incl - v;
    if (tid == 0) bsum[blockIdx.x] = wpre[16];
}

// scan3 with scan2 folded in: every block re-scans the 49 block sums in its first wave
__global__ __launch_bounds__(1024) void scan3_kernel(int* __restrict__ row_ptr,
                                                     int* __restrict__ cursor,
                                                     const int* __restrict__ bsum) {
    __shared__ int boff_s;
    __shared__ int total_s;
    int tid = threadIdx.x;
    if (tid < 64) {
        int v = (tid < SBLK) ? bsum[tid] : 0;
        int incl = v;
        #pragma unroll
        for (int off = 1; off < 64; off <<= 1) {
            int u = __shfl_up(incl, off, 64);
            if (tid >= off) incl += u;
        }
        if (tid == (int)blockIdx.x) boff_s = incl - v;
        if (tid == 63) total_s = incl;
    }
    __syncthreads();
    int i = blockIdx.x * 1024 + tid;
    if (i < NN) {
        int r = row_ptr[i] + boff_s;
        row_ptr[i] = r;
        cursor[i] = r;
    }
    if (blockIdx.x == 0 && tid == 0) row_ptr[NN] = total_s;   // == EE
}

// ---- fused scatter + layer-0 projections (grid partition: independent workloads
//      overlap on hardware; scatter needs scan3's cursor, qkvs0 needs only x) -------
// edge record: x=src, y=ea fp16(0,1), z=ea fp16(2,3), w=unused — one 16B store
// KV layout: per node, u32 slot l holds (pack(k[2l],k[2l+1]), pack(v[2l],v[2l+1]))
// as a uint2 -> half index for K at ch c: n*256 + 4*(c>>1) + (c&1); V at +2.
__global__ __launch_bounds__(256) void scatter_qkvs0_kernel(
        const int* __restrict__ srcI, const int* __restrict__ dstI,
        const float* __restrict__ ea, int* __restrict__ cursor,
        uint4* __restrict__ edges,
        const float* __restrict__ x,
        const float* __restrict__ Wq, const float* __restrict__ bq,
        const float* __restrict__ Wk, const float* __restrict__ bk,
        const float* __restrict__ Wv, const float* __restrict__ bv,
        const float* __restrict__ Ws, const float* __restrict__ bs,
        _Float16* __restrict__ Qh, _Float16* __restrict__ kvh,
        float* __restrict__ Out) {
    __shared__ __align__(16) float hs[QNPB * FIN];
    int tid = threadIdx.x;
    if (blockIdx.x < SCATB) {
        // ---------- scatter branch (no __syncthreads; per-thread early-out ok) ----
        int e = blockIdx.x * 256 + tid;
        if (e >= EE) return;
        int d = dstI[e];
        int pos = atomicAdd(&cursor[d], 1);
        float4 q = *reinterpret_cast<const float4*>(ea + (size_t)e * 4);
        uint4 rec;
        rec.x = (unsigned int)srcI[e];
        rec.y = pkh2(q.x, q.y);
        rec.z = pkh2(q.z, q.w);
        rec.w = 0u;
        edges[pos] = rec;
        return;
    }
    // ---------- qkvs0 branch: 256 threads, two matrices per thread (Q+V / K+S) ----
    int blk = blockIdx.x - SCATB;
    int g = tid >> 7, c = tid & 127;
    const float* Wa = g ? Wk : Wq; const float* ba = g ? bk : bq;
    const float* Wb = g ? Ws : Wv; const float* bb = g ? bs : bv;
    float wa[FIN], wb[FIN];
    #pragma unroll
    for (int f = 0; f < FIN; ++f) { wa[f] = Wa[f * HC + c]; wb[f] = Wb[f * HC + c]; }
    float biasa = ba[c], biasb = bb[c];
    int node0 = blk * QNPB;
    {   // float4 staging copy
        const float4* src4 = (const float4*)(x + (size_t)node0 * FIN);
        float4* dst4 = (float4*)hs;
        for (int i = tid; i < QNPB * FIN / 4; i += 256) dst4[i] = src4[i];
    }
    __syncthreads();
    const float4* hs4 = (const float4*)hs;
    int kvi = ((c >> 1) << 2) + (c & 1);      // K half-index within node row
    for (int k = 0; k < QNPB; ++k) {
        float sa = biasa, sb = biasb;
        #pragma unroll
        for (int f4 = 0; f4 < FIN / 4; ++f4) {
            float4 hv = hs4[k * (FIN / 4) + f4];
            sa += hv.x * wa[4 * f4] + hv.y * wa[4 * f4 + 1]
                + hv.z * wa[4 * f4 + 2] + hv.w * wa[4 * f4 + 3];
            sb += hv.x * wb[4 * f4] + hv.y * wb[4 * f4 + 1]
                + hv.z * wb[4 * f4 + 2] + hv.w * wb[4 * f4 + 3];
        }
        size_t n = node0 + k;
        if (g == 0) {                       // Q and V
            Qh[n * HC + c] = (_Float16)sa;
            kvh[n * 256 + kvi + 2] = (_Float16)sb;
        } else {                            // K and S
            kvh[n * 256 + kvi] = (_Float16)sa;
            Out[n * HC + c] = sb;
        }
    }
}

// ---- fused transform + projections; 256 threads (stage-T weight redundancy 4x->2x,
//      QKVS: two matrices per thread, wave-uniform split), seg-rotated T reads -------
__global__ __launch_bounds__(256) void ftq_kernel(const float* __restrict__ Wt,
        const float* __restrict__ bt,
        const float* __restrict__ Wq, const float* __restrict__ bq,
        const float* __restrict__ Wk, const float* __restrict__ bk,
        const float* __restrict__ Wv, const float* __restrict__ bv,
        const float* __restrict__ Ws, const float* __restrict__ bs,
        _Float16* __restrict__ Qh, _Float16* __restrict__ kvh,
        float* __restrict__ Out) {
    __shared__ __align__(16) float os[QNPB * HC];   // 25.6 KB
    __shared__ __align__(16) float hs[QNPB * EMB];  // 6.4 KB
    int tid = threadIdx.x;
    int node0 = blockIdx.x * QNPB;
    int g = tid >> 7;                   // 2 node-groups (2 waves each)

    {   // float4 staging copy
        const float4* src4 = (const float4*)(Out + (size_t)node0 * HC);
        float4* dst4 = (float4*)os;
        for (int i = tid; i < QNPB * HC / 4; i += 256) dst4[i] = src4[i];
    }

    // stage T: h = relu(bt + Out @ Wt). thread (g, cT=(tid&127)>>2, seg=tid&3)
    // reads rotated by seg so the 4 segs hit different bank quads each step
    int cT = (tid & 127) >> 2, seg = tid & 3;
    float wt[32];                       // slot 4*jj+t holds weight for col 4*j4(jj)+t
    #pragma unroll
    for (int jj = 0; jj < 8; ++jj) {
        int j4 = (jj + seg * 2) & 7;
        #pragma unroll
        for (int t = 0; t < 4; ++t)
            wt[4 * jj + t] = Wt[(seg * 32 + 4 * j4 + t) * EMB + cT];
    }
    float btc = bt[cT];
    __syncthreads();
    for (int k = g; k < QNPB; k += 2) {
        float p = 0.f;
        const float4* r4 = (const float4*)(os + k * HC + seg * 32);
        #pragma unroll
        for (int jj = 0; jj < 8; ++jj) {
            float4 rv = r4[(jj + seg * 2) & 7];
            p += rv.x * wt[4 * jj] + rv.y * wt[4 * jj + 1]
               + rv.z * wt[4 * jj + 2] + rv.w * wt[4 * jj + 3];
        }
        p += __shfl_xor(p, 1, 64);      // seg pairs
        p += __shfl_xor(p, 2, 64);
        if (seg == 0) hs[k * EMB + cT] = fmaxf(p + btc, 0.f);
    }
    __syncthreads();

    // stage QKVS: two matrices per thread — group 0: Q + V, group 1: K + S
    int c = tid & 127;
    const float* Wa = g ? Wk : Wq; const float* ba = g ? bk : bq;
    const float* Wb = g ? Ws : Wv; const float* bb = g ? bs : bv;
    float wa[EMB], wb[EMB];
    #pragma unroll
    for (int f = 0; f < EMB; ++f) { wa[f] = Wa[f * HC + c]; wb[f] = Wb[f * HC + c]; }
    float biasa = ba[c], biasb = bb[c];
    const float4* hs4 = (const float4*)hs;
    int kvi = ((c >> 1) << 2) + (c & 1);      // K half-index within node row
    for (int k = 0; k < QNPB; ++k) {
        float sa = biasa, sb = biasb;
        #pragma unroll
        for (int f4 = 0; f4 < EMB / 4; ++f4) {
            float4 hv = hs4[k * (EMB / 4) + f4];
            sa += hv.x * wa[4 * f4] + hv.y * wa[4 * f4 + 1]
                + hv.z * wa[4 * f4 + 2] + hv.w * wa[4 * f4 + 3];
            sb += hv.x * wb[4 * f4] + hv.y * wb[4 * f4 + 1]
                + hv.z * wb[4 * f4 + 2] + hv.w * wb[4 * f4 + 3];
        }
        size_t n = node0 + k;
        if (g == 0) {                       // Q and V
            Qh[n * HC + c] = (_Float16)sa;
            kvh[n * 256 + kvi + 2] = (_Float16)sb;
        } else {                            // K and S
            kvh[n * 256 + kvi] = (_Float16)sa;
            Out[n * HC + c] = sb;
        }
    }
}

// ------- edge attention: half-wave split, 128-thread blocks (2 waves — finer slot
//         packing for the latency-bound gathers), 8-wide main + 2-edge tail ---------
__global__ __launch_bounds__(128) void edge_attn_kernel(const int* __restrict__ row_ptr,
        const uint4* __restrict__ edges,
        const float* __restrict__ We,
        const uint2* __restrict__ Qp, const uint4* __restrict__ kvp,
        float4* __restrict__ Out) {
    int n = blockIdx.x * 2 + (threadIdx.x >> 6);   // grid*2 == NN exactly
    int lane = threadIdx.x & 63;
    int half = lane >> 5, sl = lane & 31;          // half-wave: edge slot, sub-lane
    // 4 channels per lane: c = 4*sl + j; head of all four = sl>>3
    h2 w01[4], w23[4];
    #pragma unroll
    for (int j = 0; j < 4; ++j) {
        int c = 4 * sl + j;
        w01[j] = (h2){ (_Float16)We[c],          (_Float16)We[HC + c] };
        w23[j] = (h2){ (_Float16)We[2 * HC + c], (_Float16)We[3 * HC + c] };
    }
    uint2 qw = Qp[(size_t)n * 32 + sl];
    h2 q01 = u2h(qw.x), q23 = u2h(qw.y);
    int start = row_ptr[n], end = row_ptr[n + 1];
    float z = 0.f, a0 = 0.f, a1 = 0.f, a2 = 0.f, a3 = 0.f;
    const float SC = 0.17677669529663687f;  // 1/sqrt(32)
    const char* kvb = (const char*)kvp;
    unsigned int loff = (unsigned int)sl << 4;
    int i = start;
    int main_end = start + ((end - start) & ~7);
    for (; i < main_end; i += 8) {             // 4 passes x 2 edges, no guards
        uint4 rec[4], kv[4];
        #pragma unroll
        for (int u = 0; u < 4; ++u) rec[u] = edges[i + 2 * u + half];
        #pragma unroll
        for (int u = 0; u < 4; ++u)
            kv[u] = *(const uint4*)(kvb + (((unsigned int)rec[u].x << 9) + loff));
        float p[4]; h2 ep01[4], ep23[4];
        #pragma unroll
        for (int u = 0; u < 4; ++u) {
            h2 ea01 = u2h(rec[u].y), ea23 = u2h(rec[u].z);
            float e0 = FDOT2(ea01, w01[0], FDOT2(ea23, w23[0], 0.f));
            float e1 = FDOT2(ea01, w01[1], FDOT2(ea23, w23[1], 0.f));
            float e2 = FDOT2(ea01, w01[2], FDOT2(ea23, w23[2], 0.f));
            float e3 = FDOT2(ea01, w01[3], FDOT2(ea23, w23[3], 0.f));
            ep01[u] = (h2){ (_Float16)e0, (_Float16)e1 };
            ep23[u] = (h2){ (_Float16)e2, (_Float16)e3 };
            p[u] = FDOT2(q01, u2h(kv[u].x) + ep01[u],
                   FDOT2(q23, u2h(kv[u].z) + ep23[u], 0.f));
        }
        #pragma unroll
        for (int off = 1; off < 8; off <<= 1) {   // 8-lane head groups, both halves
            #pragma unroll
            for (int u = 0; u < 4; ++u) p[u] += __shfl_xor(p[u], off, 64);
        }
        #pragma unroll
        for (int u = 0; u < 4; ++u) {
            float x = __expf(p[u] * SC);
            z += x;
            h2 v01 = u2h(kv[u].y) + ep01[u], v23 = u2h(kv[u].w) + ep23[u];
            float2 f01 = h2f2(h2u(v01)), f23 = h2f2(h2u(v23));
            a0 += x * f01.x; a1 += x * f01.y; a2 += x * f23.x; a3 += x * f23.y;
        }
    }
    for (; i < end; i += 2) {                  // tail: 2 edges per guarded pass
        int e = i + half;
        bool val = e < end;
        uint4 rec = edges[val ? e : end - 1];
        uint4 kv = *(const uint4*)(kvb + (((unsigned int)rec.x << 9) + loff));
        h2 ea01 = u2h(rec.y), ea23 = u2h(rec.z);
        float e0 = FDOT2(ea01, w01[0], FDOT2(ea23, w23[0], 0.f));
        float e1 = FDOT2(ea01, w01[1], FDOT2(ea23, w23[1], 0.f));
        float e2 = FDOT2(ea01, w01[2], FDOT2(ea23, w23[2], 0.f));
        float e3 = FDOT2(ea01, w01[3], FDOT2(ea23, w23[3], 0.f));
        h2 ep01 = { (_Float16)e0, (_Float16)e1 };
        h2 ep23 = { (_Float16)e2, (_Float16)e3 };
        float p = FDOT2(q01, u2h(kv.x) + ep01, FDOT2(q23, u2h(kv.z) + ep23, 0.f));
        #pragma unroll
        for (int off = 1; off < 8; off <<= 1) p += __shfl_xor(p, off, 64);
        float x = __expf(p * SC);
        x = val ? x : 0.f;
        z += x;
        h2 v01 = u2h(kv.y) + ep01, v23 = u2h(kv.w) + ep23;
        float2 f01 = h2f2(h2u(v01)), f23 = h2f2(h2u(v23));
        a0 += x * f01.x; a1 += x * f01.y; a2 += x * f23.x; a3 += x * f23.y;
    }
    // combine the two halves (same channels, disjoint edge sets)
    z  += __shfl_xor(z, 32, 64);
    a0 += __shfl_xor(a0, 32, 64);
    a1 += __shfl_xor(a1, 32, 64);
    a2 += __shfl_xor(a2, 32, 64);
    a3 += __shfl_xor(a3, 32, 64);
    if (half == 0) {
        float inv = 1.f / (z + 1e-16f);
        size_t oi = (size_t)n * 32 + sl;
        float4 o = Out[oi];
        o.x += a0 * inv;
        o.y += a1 * inv;
        o.z += a2 * inv;
        o.w += a3 * inv;
        Out[oi] = o;
    }
}

// ---- fused final transform + MLP head; 256 threads (halves per-block weight-load
//      fixed cost: each column loaded 2x not 4x), conflict-free rotated reads,
//      d2s aliases hs (38.4 KB LDS) ---------------------------------------------
__global__ __launch_bounds__(256) void head2_kernel(const float* __restrict__ Outb,
        const float* __restrict__ Wt, const float* __restrict__ bt,
        const float* __restrict__ W1, const float* __restrict__ b1,
        const float* __restrict__ W2, const float* __restrict__ b2,
        const float* __restrict__ W3, const float* __restrict__ b3,
        float* __restrict__ out) {
    __shared__ __align__(16) float os[QNPB * HC];   // 25.6 KB; reused as d1s
    __shared__ __align__(16) float hd[QNPB * 64];   // 12.8 KB: hs (T/1), then d2s (2/3)
    float* d1s = os;                     // alias: os dead once hs is built
    float* hs  = hd;                     // [QNPB*EMB] live stages T..1
    float* d2s = hd;                     // [QNPB*64] live stages 2..3 (hs dead)
    int tid = threadIdx.x;
    int node0 = blockIdx.x * QNPB;
    int g = tid >> 7;                    // 2 node-groups (2 waves each)

    {   // float4 staging copy
        const float4* src4 = (const float4*)(Outb + (size_t)node0 * HC);
        float4* dst4 = (float4*)os;
        for (int i = tid; i < QNPB * HC / 4; i += 256) dst4[i] = src4[i];
    }

    // stage T (seg-rotated reads, conflict-free)
    int cT = (tid & 127) >> 2, seg = tid & 3;
    float wt[32];                        // slot 4*jj+t holds weight for col 4*j4(jj)+t
    #pragma unroll
    for (int jj = 0; jj < 8; ++jj) {
        int j4 = (jj + seg * 2) & 7;
        #pragma unroll
        for (int t = 0; t < 4; ++t)
            wt[4 * jj + t] = Wt[(seg * 32 + 4 * j4 + t) * EMB + cT];
    }
    float btc = bt[cT];
    __syncthreads();
    for (int k = g; k < QNPB; k += 2) {
        float p = 0.f;
        const float4* r4 = (const float4*)(os + k * HC + seg * 32);
        #pragma unroll
        for (int jj = 0; jj < 8; ++jj) {
            float4 rv = r4[(jj + seg * 2) & 7];
            p += rv.x * wt[4 * jj] + rv.y * wt[4 * jj + 1]
               + rv.z * wt[4 * jj + 2] + rv.w * wt[4 * jj + 3];
        }
        p += __shfl_xor(p, 1, 64);
        p += __shfl_xor(p, 2, 64);
        if (seg == 0) hs[k * EMB + cT] = fmaxf(p + btc, 0.f);
    }
    __syncthreads();

    // stage 1: d1 = relu(b1 + h @ W1)
    int c1 = tid & 127;
    float w1[32];
    #pragma unroll
    for (int f = 0; f < 32; ++f) w1[f] = W1[f * DENSE + c1];
    float b1c = b1[c1];
    const float4* hs4 = (const float4*)hs;
    for (int k = g; k < QNPB; k += 2) {
        float s = b1c;
        #pragma unroll
        for (int f4 = 0; f4 < 8; ++f4) {
            float4 hv = hs4[k * 8 + f4];
            s += hv.x * w1[4 * f4] + hv.y * w1[4 * f4 + 1]
               + hv.z * w1[4 * f4 + 2] + hv.w * w1[4 * f4 + 3];
        }
        d1s[k * DENSE + c1] = fmaxf(s, 0.f);
    }
    __syncthreads();

    // stage 2: d2 = relu(b2 + d1 @ W2); hh-rotated reads (disjoint bank quads)
    int c2 = (tid & 127) >> 1, hh = tid & 1;
    float w2[64];                        // slot 4*jj+t holds weight for col 4*j4(jj)+t
    #pragma unroll
    for (int jj = 0; jj < 16; ++jj) {
        int j4 = (jj + hh) & 15;
        #pragma unroll
        for (int t = 0; t < 4; ++t)
            w2[4 * jj + t] = W2[(hh * 64 + 4 * j4 + t) * 64 + c2];
    }
    float b2c = b2[c2];
    for (int k = g; k < QNPB; k += 2) {
        float p = 0.f;
        const float4* r4 = (const float4*)(d1s + k * DENSE + hh * 64);
        #pragma unroll
        for (int jj = 0; jj < 16; ++jj) {
            float4 rv = r4[(jj + hh) & 15];
            p += rv.x * w2[4 * jj] + rv.y * w2[4 * jj + 1]
               + rv.z * w2[4 * jj + 2] + rv.w * w2[4 * jj + 3];
        }
        p += __shfl_xor(p, 1, 64);
        if (hh == 0) d2s[k * 64 + c2] = fmaxf(p + b2c, 0.f);
    }
    __syncthreads();

    // stage 3
    int w = tid >> 6, lane = tid & 63;   // 4 waves
    float w3r = W3[lane];
    float b3r = b3[0];
    for (int k = w; k < QNPB; k += 4) {
        float t = d2s[k * 64 + lane] * w3r;
        #pragma unroll
        for (int off = 1; off < 64; off <<= 1) t += __shfl_xor(t, off, 64);
        if (lane == 0) out[node0 + k] = 1.f / (1.f + __expf(-(t + b3r)));
    }
}

extern "C" void kernel_launch(void* const* d_in, const int* in_sizes, int n_in,
                              void* d_out, int out_size, void* d_ws, size_t ws_size,
                              hipStream_t stream) {
    const float* x   = (const float*)d_in[0];
    const int*   ei  = (const int*)d_in[1];    // [2,E]: src=ei, dst=ei+E
    const float* ea  = (const float*)d_in[2];
    const float* Wq0 = (const float*)d_in[3];  const float* bq0 = (const float*)d_in[4];
    const float* Wk0 = (const float*)d_in[5];  const float* bk0 = (const float*)d_in[6];
    const float* Wv0 = (const float*)d_in[7];  const float* bv0 = (const float*)d_in[8];
    const float* We0 = (const float*)d_in[9];
    const float* Ws0 = (const float*)d_in[10]; const float* bs0 = (const float*)d_in[11];
    const float* Wt0 = (const float*)d_in[12]; const float* bt0 = (const float*)d_in[13];
    const float* WqL = (const float*)d_in[14]; const float* bqL = (const float*)d_in[15];
    const float* WkL = (const float*)d_in[16]; const float* bkL = (const float*)d_in[17];
    const float* WvL = (const float*)d_in[18]; const float* bvL = (const float*)d_in[19];
    const float* WeL = (const float*)d_in[20];
    const float* WsL = (const float*)d_in[21]; const float* bsL = (const float*)d_in[22];
    const float* WtL = (const float*)d_in[23]; const float* btL = (const float*)d_in[24];
    const float* W1  = (const float*)d_in[25]; const float* b1  = (const float*)d_in[26];
    const float* W2  = (const float*)d_in[27]; const float* b2  = (const float*)d_in[28];
    const float* W3  = (const float*)d_in[29]; const float* b3  = (const float*)d_in[30];
    float* out = (float*)d_out;

    char* ws = (char*)d_ws;
    size_t off = 0;
    auto alloc = [&](size_t bytes) -> void* {
        void* p = ws + off; off = (off + bytes + 255) & ~(size_t)255; return p;
    };
    int*      cursor  = (int*)     alloc((size_t)NN * 4);
    int*      row_ptr = (int*)     alloc((size_t)(NN + 1) * 4);
    int*      bsum    = (int*)     alloc((size_t)SBLK * 4);
    uint4*    edges   = (uint4*)   alloc((size_t)EE * 16);
    _Float16* Qh      = (_Float16*)alloc((size_t)NN * HC * 2);
    _Float16* kvh     = (_Float16*)alloc((size_t)NN * HC * 2 * 2);  // (k,k,v,v) per pair
    float*    Outb    = (float*)   alloc((size_t)NN * HC * 4);
    // total ~77 MB

    // ---- CSR by dst (edge_index shared by all 3 conv layers) ----
    hipMemsetAsync(cursor, 0, (size_t)NN * 4, stream);
    hist_kernel<<<(EE + 255) / 256, 256, 0, stream>>>(ei + EE, cursor);
    scan1_kernel<<<SBLK, 1024, 0, stream>>>(cursor, row_ptr, bsum);
    scan3_kernel<<<SBLK, 1024, 0, stream>>>(row_ptr, cursor, bsum);   // scan2 folded in

    const uint4* kvp4 = (const uint4*)kvh;
    const uint2* Qp2 = (const uint2*)Qh;
    float4* Out4 = (float4*)Outb;

    // ---- fused scatter + layer-0 projections (independent workloads overlap) ----
    scatter_qkvs0_kernel<<<SCATB + NN / QNPB, 256, 0, stream>>>(
        ei, ei + EE, ea, cursor, edges,
        x, Wq0, bq0, Wk0, bk0, Wv0, bv0, Ws0, bs0, Qh, kvh, Outb);
    edge_attn_kernel<<<NN / 2, 128, 0, stream>>>(row_ptr, edges, We0, Qp2, kvp4, Out4);

    // ---- layer 1 ----
    ftq_kernel<<<NN / QNPB, 256, 0, stream>>>(Wt0, bt0,
        WqL, bqL, WkL, bkL, WvL, bvL, WsL, bsL, Qh, kvh, Outb);
    edge_attn_kernel<<<NN / 2, 128, 0, stream>>>(row_ptr, edges, WeL, Qp2, kvp4, Out4);

    // ---- layer 2 ----
    ftq_kernel<<<NN / QNPB, 256, 0, stream>>>(WtL, btL,
        WqL + EMB * HC, bqL + HC, WkL + EMB * HC, bkL + HC,
        WvL + EMB * HC, bvL + HC, WsL + EMB * HC, bsL + HC, Qh, kvh, Outb);
    edge_attn_kernel<<<NN / 2, 128, 0, stream>>>(row_ptr, edges,
        WeL + EDIM * HC, Qp2, kvp4, Out4);

    // ---- fused final transform + register-weight MLP head ----
    head2_kernel<<<NN / QNPB, 256, 0, stream>>>(Outb, WtL + (size_t)HC * EMB, btL + EMB,
                                                W1, b1, W2, b2, W3, b3, out);
}

// Round 16
// 544.377 us; speedup vs baseline: 1.0140x; 1.0140x over previous
//
#include <hip/hip_runtime.h>

#define NN 50000
#define EE 800000
#define FIN 16
#define EDIM 4
#define EMB 32
#define NH 4
#define HC 128          // EMB*NH
#define NL 2
#define DENSE 128
#define QNPB 50         // nodes per qkvs/ftq/head block (50000 = 1000 * 50)
#define SBLK 49         // scan blocks: ceil(50000/1024)

typedef _Float16 h2 __attribute__((ext_vector_type(2)));
union HU { unsigned int u; h2 h; };

__device__ __forceinline__ h2 u2h(unsigned int u) { HU c; c.u = u; return c.h; }
__device__ __forceinline__ unsigned int h2u(h2 h) { HU c; c.h = h; return c.u; }

// fdot2: f32 += h2 . h2 — hedge builtin availability with a scalar fallback
#if defined(__has_builtin)
#  if __has_builtin(__builtin_amdgcn_fdot2)
#    define FDOT2(a, b, c) __builtin_amdgcn_fdot2((a), (b), (c), false)
#  endif
#endif
#ifndef FDOT2
__device__ __forceinline__ float fdot2_sw(h2 a, h2 b, float c) {
    return fmaf((float)a.x, (float)b.x, fmaf((float)a.y, (float)b.y, c));
}
#  define FDOT2(a, b, c) fdot2_sw((a), (b), (c))
#endif

// unpack two packed fp16 -> float2
__device__ __forceinline__ float2 h2f2(unsigned int u) {
    union { unsigned int u; _Float16 h[2]; } c; c.u = u;
    return make_float2((float)c.h[0], (float)c.h[1]);
}
__device__ __forceinline__ unsigned int pkh2(float a, float b) {
    union { unsigned int u; _Float16 h[2]; } c;
    c.h[0] = (_Float16)a; c.h[1] = (_Float16)b; return c.u;
}

// ---------------- CSR build ----------------
__global__ void hist_kernel(const int* __restrict__ dst, int* __restrict__ counts) {
    int e = blockIdx.x * blockDim.x + threadIdx.x;
    if (e < EE) atomicAdd(&counts[dst[e]], 1);
}

__global__ __launch_bounds__(1024) void scan1_kernel(const int* __restrict__ cursor,
                                                     int* __restrict__ row_ptr,
                                                     int* __restrict__ bsum) {
    __shared__ int wsum[16];
    __shared__ int wpre[17];
    int tid = threadIdx.x, lane = tid & 63, wid = tid >> 6;
    int i = blockIdx.x * 1024 + tid;
    int v = (i < NN) ? cursor[i] : 0;
    int incl = v;
    #pragma unroll
    for (int off = 1; off < 64; off <<= 1) {
        int t = __shfl_up(incl, off, 64);
        if (lane >= off) incl += t;
    }
    if (lane == 63) wsum[wid] = incl;
    __syncthreads();
    if (tid == 0) {
        int acc = 0;
        #pragma unroll
        for (int w = 0; w < 16; ++w) { wpre[w] = acc; acc += wsum[w]; }
        wpre[16] = acc;
    }
    __syncthreads();
    if (i < NN) row_ptr[i] = wpre[wid] + incl - v;
    if (tid == 0) bsum[blockIdx.x] = wpre[16];
}

// scan3 with scan2 folded in: every block re-scans the 49 block sums in its first wave
__global__ __launch_bounds__(1024) void scan3_kernel(int* __restrict__ row_ptr,
                                                     int* __restrict__ cursor,
                                                     const int* __restrict__ bsum) {
    __shared__ int boff_s;
    __shared__ int total_s;
    int tid = threadIdx.x;
    if (tid < 64) {
        int v = (tid < SBLK) ? bsum[tid] : 0;
        int incl = v;
        #pragma unroll
        for (int off = 1; off < 64; off <<= 1) {
            int u = __shfl_up(incl, off, 64);
            if (tid >= off) incl += u;
        }
        if (tid == (int)blockIdx.x) boff_s = incl - v;
        if (tid == 63) total_s = incl;
    }
    __syncthreads();
    int i = blockIdx.x * 1024 + tid;
    if (i < NN) {
        int r = row_ptr[i] + boff_s;
        row_ptr[i] = r;
        cursor[i] = r;
    }
    if (blockIdx.x == 0 && tid == 0) row_ptr[NN] = total_s;   // == EE
}

// edge record: x=src, y=ea fp16(0,1), z=ea fp16(2,3), w=unused — one 16B store
__global__ void scatter_kernel(const int* __restrict__ src, const int* __restrict__ dst,
                               const float* __restrict__ ea, int* __restrict__ cursor,
                               uint4* __restrict__ edges) {
    int e = blockIdx.x * blockDim.x + threadIdx.x;
    if (e >= EE) return;
    int d = dst[e];
    int pos = atomicAdd(&cursor[d], 1);
    float4 q = *reinterpret_cast<const float4*>(ea + (size_t)e * 4);
    uint4 rec;
    rec.x = (unsigned int)src[e];
    rec.y = pkh2(q.x, q.y);
    rec.z = pkh2(q.z, q.w);
    rec.w = 0u;
    edges[pos] = rec;
}

// ------- layer-0 projections: 256 threads, two matrices per thread (Q+V / K+S) ------
// KV layout: per node, u32 slot l holds (pack(k[2l],k[2l+1]), pack(v[2l],v[2l+1]))
// as a uint2 -> half index for K at ch c: n*256 + 4*(c>>1) + (c&1); V at +2.
// Per lane sl (4 ch): uint4 at byte sl*16 = (k01,v01,k23,v23).
__global__ __launch_bounds__(256) void qkvs0_kernel(const float* __restrict__ x,
        const float* __restrict__ Wq, const float* __restrict__ bq,
        const float* __restrict__ Wk, const float* __restrict__ bk,
        const float* __restrict__ Wv, const float* __restrict__ bv,
        const float* __restrict__ Ws, const float* __restrict__ bs,
        _Float16* __restrict__ Qh, _Float16* __restrict__ kvh,
        float* __restrict__ Out) {
    __shared__ __align__(16) float hs[QNPB * FIN];
    int tid = threadIdx.x;
    int g = tid >> 7, c = tid & 127;
    const float* Wa = g ? Wk : Wq; const float* ba = g ? bk : bq;
    const float* Wb = g ? Ws : Wv; const float* bb = g ? bs : bv;
    float wa[FIN], wb[FIN];
    #pragma unroll
    for (int f = 0; f < FIN; ++f) { wa[f] = Wa[f * HC + c]; wb[f] = Wb[f * HC + c]; }
    float biasa = ba[c], biasb = bb[c];
    int node0 = blockIdx.x * QNPB;
    {   // float4 staging copy
        const float4* src4 = (const float4*)(x + (size_t)node0 * FIN);
        float4* dst4 = (float4*)hs;
        for (int i = tid; i < QNPB * FIN / 4; i += 256) dst4[i] = src4[i];
    }
    __syncthreads();
    const float4* hs4 = (const float4*)hs;
    int kvi = ((c >> 1) << 2) + (c & 1);      // K half-index within node row
    for (int k = 0; k < QNPB; ++k) {
        float sa = biasa, sb = biasb;
        #pragma unroll
        for (int f4 = 0; f4 < FIN / 4; ++f4) {
            float4 hv = hs4[k * (FIN / 4) + f4];
            sa += hv.x * wa[4 * f4] + hv.y * wa[4 * f4 + 1]
                + hv.z * wa[4 * f4 + 2] + hv.w * wa[4 * f4 + 3];
            sb += hv.x * wb[4 * f4] + hv.y * wb[4 * f4 + 1]
                + hv.z * wb[4 * f4 + 2] + hv.w * wb[4 * f4 + 3];
        }
        size_t n = node0 + k;
        if (g == 0) {                       // Q and V
            Qh[n * HC + c] = (_Float16)sa;
            kvh[n * 256 + kvi + 2] = (_Float16)sb;
        } else {                            // K and S
            kvh[n * 256 + kvi] = (_Float16)sa;
            Out[n * HC + c] = sb;
        }
    }
}

// ---- fused transform + projections; 256 threads (stage-T weight redundancy 4x->2x,
//      QKVS: two matrices per thread, wave-uniform split), seg-rotated T reads -------
__global__ __launch_bounds__(256) void ftq_kernel(const float* __restrict__ Wt,
        const float* __restrict__ bt,
        const float* __restrict__ Wq, const float* __restrict__ bq,
        const float* __restrict__ Wk, const float* __restrict__ bk,
        const float* __restrict__ Wv, const float* __restrict__ bv,
        const float* __restrict__ Ws, const float* __restrict__ bs,
        _Float16* __restrict__ Qh, _Float16* __restrict__ kvh,
        float* __restrict__ Out) {
    __shared__ __align__(16) float os[QNPB * HC];   // 25.6 KB
    __shared__ __align__(16) float hs[QNPB * EMB];  // 6.4 KB
    int tid = threadIdx.x;
    int node0 = blockIdx.x * QNPB;
    int g = tid >> 7;                   // 2 node-groups (2 waves each)

    {   // float4 staging copy
        const float4* src4 = (const float4*)(Out + (size_t)node0 * HC);
        float4* dst4 = (float4*)os;
        for (int i = tid; i < QNPB * HC / 4; i += 256) dst4[i] = src4[i];
    }

    // stage T: h = relu(bt + Out @ Wt). thread (g, cT=(tid&127)>>2, seg=tid&3)
    // reads rotated by seg so the 4 segs hit different bank quads each step
    int cT = (tid & 127) >> 2, seg = tid & 3;
    float wt[32];                       // slot 4*jj+t holds weight for col 4*j4(jj)+t
    #pragma unroll
    for (int jj = 0; jj < 8; ++jj) {
        int j4 = (jj + seg * 2) & 7;
        #pragma unroll
        for (int t = 0; t < 4; ++t)
            wt[4 * jj + t] = Wt[(seg * 32 + 4 * j4 + t) * EMB + cT];
    }
    float btc = bt[cT];
    __syncthreads();
    for (int k = g; k < QNPB; k += 2) {
        float p = 0.f;
        const float4* r4 = (const float4*)(os + k * HC + seg * 32);
        #pragma unroll
        for (int jj = 0; jj < 8; ++jj) {
            float4 rv = r4[(jj + seg * 2) & 7];
            p += rv.x * wt[4 * jj] + rv.y * wt[4 * jj + 1]
               + rv.z * wt[4 * jj + 2] + rv.w * wt[4 * jj + 3];
        }
        p += __shfl_xor(p, 1, 64);      // seg pairs
        p += __shfl_xor(p, 2, 64);
        if (seg == 0) hs[k * EMB + cT] = fmaxf(p + btc, 0.f);
    }
    __syncthreads();

    // stage QKVS: two matrices per thread — group 0: Q + V, group 1: K + S
    int c = tid & 127;
    const float* Wa = g ? Wk : Wq; const float* ba = g ? bk : bq;
    const float* Wb = g ? Ws : Wv; const float* bb = g ? bs : bv;
    float wa[EMB], wb[EMB];
    #pragma unroll
    for (int f = 0; f < EMB; ++f) { wa[f] = Wa[f * HC + c]; wb[f] = Wb[f * HC + c]; }
    float biasa = ba[c], biasb = bb[c];
    const float4* hs4 = (const float4*)hs;
    int kvi = ((c >> 1) << 2) + (c & 1);      // K half-index within node row
    for (int k = 0; k < QNPB; ++k) {
        float sa = biasa, sb = biasb;
        #pragma unroll
        for (int f4 = 0; f4 < EMB / 4; ++f4) {
            float4 hv = hs4[k * (EMB / 4) + f4];
            sa += hv.x * wa[4 * f4] + hv.y * wa[4 * f4 + 1]
                + hv.z * wa[4 * f4 + 2] + hv.w * wa[4 * f4 + 3];
            sb += hv.x * wb[4 * f4] + hv.y * wb[4 * f4 + 1]
                + hv.z * wb[4 * f4 + 2] + hv.w * wb[4 * f4 + 3];
        }
        size_t n = node0 + k;
        if (g == 0) {                       // Q and V
            Qh[n * HC + c] = (_Float16)sa;
            kvh[n * 256 + kvi + 2] = (_Float16)sb;
        } else {                            // K and S
            kvh[n * 256 + kvi] = (_Float16)sa;
            Out[n * HC + c] = sb;
        }
    }
}

// ------- edge attention: half-wave split, 128-thread blocks (2 waves — finer slot
//         packing for the latency-bound gathers), 8-wide main + 2-edge tail ---------
__global__ __launch_bounds__(128) void edge_attn_kernel(const int* __restrict__ row_ptr,
        const uint4* __restrict__ edges,
        const float* __restrict__ We,
        const uint2* __restrict__ Qp, const uint4* __restrict__ kvp,
        float4* __restrict__ Out) {
    int n = blockIdx.x * 2 + (threadIdx.x >> 6);   // grid*2 == NN exactly
    int lane = threadIdx.x & 63;
    int half = lane >> 5, sl = lane & 31;          // half-wave: edge slot, sub-lane
    // 4 channels per lane: c = 4*sl + j; head of all four = sl>>3
    h2 w01[4], w23[4];
    #pragma unroll
    for (int j = 0; j < 4; ++j) {
        int c = 4 * sl + j;
        w01[j] = (h2){ (_Float16)We[c],          (_Float16)We[HC + c] };
        w23[j] = (h2){ (_Float16)We[2 * HC + c], (_Float16)We[3 * HC + c] };
    }
    uint2 qw = Qp[(size_t)n * 32 + sl];
    h2 q01 = u2h(qw.x), q23 = u2h(qw.y);
    int start = row_ptr[n], end = row_ptr[n + 1];
    float z = 0.f, a0 = 0.f, a1 = 0.f, a2 = 0.f, a3 = 0.f;
    const float SC = 0.17677669529663687f;  // 1/sqrt(32)
    const char* kvb = (const char*)kvp;
    unsigned int loff = (unsigned int)sl << 4;
    int i = start;
    int main_end = start + ((end - start) & ~7);
    for (; i < main_end; i += 8) {             // 4 passes x 2 edges, no guards
        uint4 rec[4], kv[4];
        #pragma unroll
        for (int u = 0; u < 4; ++u) rec[u] = edges[i + 2 * u + half];
        #pragma unroll
        for (int u = 0; u < 4; ++u)
            kv[u] = *(const uint4*)(kvb + (((unsigned int)rec[u].x << 9) + loff));
        float p[4]; h2 ep01[4], ep23[4];
        #pragma unroll
        for (int u = 0; u < 4; ++u) {
            h2 ea01 = u2h(rec[u].y), ea23 = u2h(rec[u].z);
            float e0 = FDOT2(ea01, w01[0], FDOT2(ea23, w23[0], 0.f));
            float e1 = FDOT2(ea01, w01[1], FDOT2(ea23, w23[1], 0.f));
            float e2 = FDOT2(ea01, w01[2], FDOT2(ea23, w23[2], 0.f));
            float e3 = FDOT2(ea01, w01[3], FDOT2(ea23, w23[3], 0.f));
            ep01[u] = (h2){ (_Float16)e0, (_Float16)e1 };
            ep23[u] = (h2){ (_Float16)e2, (_Float16)e3 };
            p[u] = FDOT2(q01, u2h(kv[u].x) + ep01[u],
                   FDOT2(q23, u2h(kv[u].z) + ep23[u], 0.f));
        }
        #pragma unroll
        for (int off = 1; off < 8; off <<= 1) {   // 8-lane head groups, both halves
            #pragma unroll
            for (int u = 0; u < 4; ++u) p[u] += __shfl_xor(p[u], off, 64);
        }
        #pragma unroll
        for (int u = 0; u < 4; ++u) {
            float x = __expf(p[u] * SC);
            z += x;
            h2 v01 = u2h(kv[u].y) + ep01[u], v23 = u2h(kv[u].w) + ep23[u];
            float2 f01 = h2f2(h2u(v01)), f23 = h2f2(h2u(v23));
            a0 += x * f01.x; a1 += x * f01.y; a2 += x * f23.x; a3 += x * f23.y;
        }
    }
    for (; i < end; i += 2) {                  // tail: 2 edges per guarded pass
        int e = i + half;
        bool val = e < end;
        uint4 rec = edges[val ? e : end - 1];
        uint4 kv = *(const uint4*)(kvb + (((unsigned int)rec.x << 9) + loff));
        h2 ea01 = u2h(rec.y), ea23 = u2h(rec.z);
        float e0 = FDOT2(ea01, w01[0], FDOT2(ea23, w23[0], 0.f));
        float e1 = FDOT2(ea01, w01[1], FDOT2(ea23, w23[1], 0.f));
        float e2 = FDOT2(ea01, w01[2], FDOT2(ea23, w23[2], 0.f));
        float e3 = FDOT2(ea01, w01[3], FDOT2(ea23, w23[3], 0.f));
        h2 ep01 = { (_Float16)e0, (_Float16)e1 };
        h2 ep23 = { (_Float16)e2, (_Float16)e3 };
        float p = FDOT2(q01, u2h(kv.x) + ep01, FDOT2(q23, u2h(kv.z) + ep23, 0.f));
        #pragma unroll
        for (int off = 1; off < 8; off <<= 1) p += __shfl_xor(p, off, 64);
        float x = __expf(p * SC);
        x = val ? x : 0.f;
        z += x;
        h2 v01 = u2h(kv.y) + ep01, v23 = u2h(kv.w) + ep23;
        float2 f01 = h2f2(h2u(v01)), f23 = h2f2(h2u(v23));
        a0 += x * f01.x; a1 += x * f01.y; a2 += x * f23.x; a3 += x * f23.y;
    }
    // combine the two halves (same channels, disjoint edge sets)
    z  += __shfl_xor(z, 32, 64);
    a0 += __shfl_xor(a0, 32, 64);
    a1 += __shfl_xor(a1, 32, 64);
    a2 += __shfl_xor(a2, 32, 64);
    a3 += __shfl_xor(a3, 32, 64);
    if (half == 0) {
        float inv = 1.f / (z + 1e-16f);
        size_t oi = (size_t)n * 32 + sl;
        float4 o = Out[oi];
        o.x += a0 * inv;
        o.y += a1 * inv;
        o.z += a2 * inv;
        o.w += a3 * inv;
        Out[oi] = o;
    }
}

// ---- fused final transform + MLP head; 256 threads (halves per-block weight-load
//      fixed cost: each column loaded 2x not 4x), conflict-free rotated reads,
//      d2s aliases hs (38.4 KB LDS) ---------------------------------------------
__global__ __launch_bounds__(256) void head2_kernel(const float* __restrict__ Outb,
        const float* __restrict__ Wt, const float* __restrict__ bt,
        const float* __restrict__ W1, const float* __restrict__ b1,
        const float* __restrict__ W2, const float* __restrict__ b2,
        const float* __restrict__ W3, const float* __restrict__ b3,
        float* __restrict__ out) {
    __shared__ __align__(16) float os[QNPB * HC];   // 25.6 KB; reused as d1s
    __shared__ __align__(16) float hd[QNPB * 64];   // 12.8 KB: hs (T/1), then d2s (2/3)
    float* d1s = os;                     // alias: os dead once hs is built
    float* hs  = hd;                     // [QNPB*EMB] live stages T..1
    float* d2s = hd;                     // [QNPB*64] live stages 2..3 (hs dead)
    int tid = threadIdx.x;
    int node0 = blockIdx.x * QNPB;
    int g = tid >> 7;                    // 2 node-groups (2 waves each)

    {   // float4 staging copy
        const float4* src4 = (const float4*)(Outb + (size_t)node0 * HC);
        float4* dst4 = (float4*)os;
        for (int i = tid; i < QNPB * HC / 4; i += 256) dst4[i] = src4[i];
    }

    // stage T (seg-rotated reads, conflict-free)
    int cT = (tid & 127) >> 2, seg = tid & 3;
    float wt[32];                        // slot 4*jj+t holds weight for col 4*j4(jj)+t
    #pragma unroll
    for (int jj = 0; jj < 8; ++jj) {
        int j4 = (jj + seg * 2) & 7;
        #pragma unroll
        for (int t = 0; t < 4; ++t)
            wt[4 * jj + t] = Wt[(seg * 32 + 4 * j4 + t) * EMB + cT];
    }
    float btc = bt[cT];
    __syncthreads();
    for (int k = g; k < QNPB; k += 2) {
        float p = 0.f;
        const float4* r4 = (const float4*)(os + k * HC + seg * 32);
        #pragma unroll
        for (int jj = 0; jj < 8; ++jj) {
            float4 rv = r4[(jj + seg * 2) & 7];
            p += rv.x * wt[4 * jj] + rv.y * wt[4 * jj + 1]
               + rv.z * wt[4 * jj + 2] + rv.w * wt[4 * jj + 3];
        }
        p += __shfl_xor(p, 1, 64);
        p += __shfl_xor(p, 2, 64);
        if (seg == 0) hs[k * EMB + cT] = fmaxf(p + btc, 0.f);
    }
    __syncthreads();

    // stage 1: d1 = relu(b1 + h @ W1)
    int c1 = tid & 127;
    float w1[32];
    #pragma unroll
    for (int f = 0; f < 32; ++f) w1[f] = W1[f * DENSE + c1];
    float b1c = b1[c1];
    const float4* hs4 = (const float4*)hs;
    for (int k = g; k < QNPB; k += 2) {
        float s = b1c;
        #pragma unroll
        for (int f4 = 0; f4 < 8; ++f4) {
            float4 hv = hs4[k * 8 + f4];
            s += hv.x * w1[4 * f4] + hv.y * w1[4 * f4 + 1]
               + hv.z * w1[4 * f4 + 2] + hv.w * w1[4 * f4 + 3];
        }
        d1s[k * DENSE + c1] = fmaxf(s, 0.f);
    }
    __syncthreads();

    // stage 2: d2 = relu(b2 + d1 @ W2); hh-rotated reads (disjoint bank quads)
    int c2 = (tid & 127) >> 1, hh = tid & 1;
    float w2[64];                        // slot 4*jj+t holds weight for col 4*j4(jj)+t
    #pragma unroll
    for (int jj = 0; jj < 16; ++jj) {
        int j4 = (jj + hh) & 15;
        #pragma unroll
        for (int t = 0; t < 4; ++t)
            w2[4 * jj + t] = W2[(hh * 64 + 4 * j4 + t) * 64 + c2];
    }
    float b2c = b2[c2];
    for (int k = g; k < QNPB; k += 2) {
        float p = 0.f;
        const float4* r4 = (const float4*)(d1s + k * DENSE + hh * 64);
        #pragma unroll
        for (int jj = 0; jj < 16; ++jj) {
            float4 rv = r4[(jj + hh) & 15];
            p += rv.x * w2[4 * jj] + rv.y * w2[4 * jj + 1]
               + rv.z * w2[4 * jj + 2] + rv.w * w2[4 * jj + 3];
        }
        p += __shfl_xor(p, 1, 64);
        if (hh == 0) d2s[k * 64 + c2] = fmaxf(p + b2c, 0.f);
    }
    __syncthreads();

    // stage 3
    int w = tid >> 6, lane = tid & 63;   // 4 waves
    float w3r = W3[lane];
    float b3r = b3[0];
    for (int k = w; k < QNPB; k += 4) {
        float t = d2s[k * 64 + lane] * w3r;
        #pragma unroll
        for (int off = 1; off < 64; off <<= 1) t += __shfl_xor(t, off, 64);
        if (lane == 0) out[node0 + k] = 1.f / (1.f + __expf(-(t + b3r)));
    }
}

extern "C" void kernel_launch(void* const* d_in, const int* in_sizes, int n_in,
                              void* d_out, int out_size, void* d_ws, size_t ws_size,
                              hipStream_t stream) {
    const float* x   = (const float*)d_in[0];
    const int*   ei  = (const int*)d_in[1];    // [2,E]: src=ei, dst=ei+E
    const float* ea  = (const float*)d_in[2];
    const float* Wq0 = (const float*)d_in[3];  const float* bq0 = (const float*)d_in[4];
    const float* Wk0 = (const float*)d_in[5];  const float* bk0 = (const float*)d_in[6];
    const float* Wv0 = (const float*)d_in[7];  const float* bv0 = (const float*)d_in[8];
    const float* We0 = (const float*)d_in[9];
    const float* Ws0 = (const float*)d_in[10]; const float* bs0 = (const float*)d_in[11];
    const float* Wt0 = (const float*)d_in[12]; const float* bt0 = (const float*)d_in[13];
    const float* WqL = (const float*)d_in[14]; const float* bqL = (const float*)d_in[15];
    const float* WkL = (const float*)d_in[16]; const float* bkL = (const float*)d_in[17];
    const float* WvL = (const float*)d_in[18]; const float* bvL = (const float*)d_in[19];
    const float* WeL = (const float*)d_in[20];
    const float* WsL = (const float*)d_in[21]; const float* bsL = (const float*)d_in[22];
    const float* WtL = (const float*)d_in[23]; const float* btL = (const float*)d_in[24];
    const float* W1  = (const float*)d_in[25]; const float* b1  = (const float*)d_in[26];
    const float* W2  = (const float*)d_in[27]; const float* b2  = (const float*)d_in[28];
    const float* W3  = (const float*)d_in[29]; const float* b3  = (const float*)d_in[30];
    float* out = (float*)d_out;

    char* ws = (char*)d_ws;
    size_t off = 0;
    auto alloc = [&](size_t bytes) -> void* {
        void* p = ws + off; off = (off + bytes + 255) & ~(size_t)255; return p;
    };
    int*      cursor  = (int*)     alloc((size_t)NN * 4);
    int*      row_ptr = (int*)     alloc((size_t)(NN + 1) * 4);
    int*      bsum    = (int*)     alloc((size_t)SBLK * 4);
    uint4*    edges   = (uint4*)   alloc((size_t)EE * 16);
    _Float16* Qh      = (_Float16*)alloc((size_t)NN * HC * 2);
    _Float16* kvh     = (_Float16*)alloc((size_t)NN * HC * 2 * 2);  // (k,k,v,v) per pair
    float*    Outb    = (float*)   alloc((size_t)NN * HC * 4);
    // total ~77 MB

    // ---- CSR by dst (edge_index shared by all 3 conv layers) ----
    hipMemsetAsync(cursor, 0, (size_t)NN * 4, stream);
    hist_kernel<<<(EE + 255) / 256, 256, 0, stream>>>(ei + EE, cursor);
    scan1_kernel<<<SBLK, 1024, 0, stream>>>(cursor, row_ptr, bsum);
    scan3_kernel<<<SBLK, 1024, 0, stream>>>(row_ptr, cursor, bsum);   // scan2 folded in
    scatter_kernel<<<(EE + 255) / 256, 256, 0, stream>>>(ei, ei + EE, ea, cursor, edges);

    const uint4* kvp4 = (const uint4*)kvh;
    const uint2* Qp2 = (const uint2*)Qh;
    float4* Out4 = (float4*)Outb;

    // ---- layer 0 ----
    qkvs0_kernel<<<NN / QNPB, 256, 0, stream>>>(x, Wq0, bq0, Wk0, bk0, Wv0, bv0,
                                                Ws0, bs0, Qh, kvh, Outb);
    edge_attn_kernel<<<NN / 2, 128, 0, stream>>>(row_ptr, edges, We0, Qp2, kvp4, Out4);

    // ---- layer 1 ----
    ftq_kernel<<<NN / QNPB, 256, 0, stream>>>(Wt0, bt0,
        WqL, bqL, WkL, bkL, WvL, bvL, WsL, bsL, Qh, kvh, Outb);
    edge_attn_kernel<<<NN / 2, 128, 0, stream>>>(row_ptr, edges, WeL, Qp2, kvp4, Out4);

    // ---- layer 2 ----
    ftq_kernel<<<NN / QNPB, 256, 0, stream>>>(WtL, btL,
        WqL + EMB * HC, bqL + HC, WkL + EMB * HC, bkL + HC,
        WvL + EMB * HC, bvL + HC, WsL + EMB * HC, bsL + HC, Qh, kvh, Outb);
    edge_attn_kernel<<<NN / 2, 128, 0, stream>>>(row_ptr, edges,
        WeL + EDIM * HC, Qp2, kvp4, Out4);

    // ---- fused final transform + register-weight MLP head ----
    head2_kernel<<<NN / QNPB, 256, 0, stream>>>(Outb, WtL + (size_t)HC * EMB, btL + EMB,
                                                W1, b1, W2, b2, W3, b3, out);
}